// Round 1
// baseline (1538.454 us; speedup 1.0000x reference)
//
#include <hip/hip_runtime.h>
#include <cstdint>

typedef _Float16 h8 __attribute__((ext_vector_type(8)));
typedef _Float16 h4 __attribute__((ext_vector_type(4)));
typedef float    f4 __attribute__((ext_vector_type(4)));

static constexpr int  Mdim = 8192;   // B*S rows
static constexpr int  Ndim = 8192;   // D_OUT
static constexpr int  Kdim = 2048;   // D_IN
static constexpr int  BM = 128, BN = 128, BK = 64;
static constexpr long long OFF_SCORES = 67108864LL;   // region 1: scores
static constexpr long long OFF_OUT    = 134217728LL;  // region 2: output

__device__ __forceinline__ void gld_lds16(const void* g, void* l) {
  __builtin_amdgcn_global_load_lds(
      (__attribute__((address_space(1))) void*)(uintptr_t)g,
      (__attribute__((address_space(3))) void*)l, 16, 0, 0);
}

// ---- prep: x fp32 -> fp16 -------------------------------------------------
__global__ __launch_bounds__(256) void prep_x(const float* __restrict__ x,
                                              _Float16* __restrict__ xh) {
  const long long i = (long long)(blockIdx.x * blockDim.x + threadIdx.x) * 4;
  f4 v = *(const f4*)(x + i);
  h4 h;
  h[0] = (_Float16)v[0]; h[1] = (_Float16)v[1];
  h[2] = (_Float16)v[2]; h[3] = (_Float16)v[3];
  *(h4*)(xh + i) = h;
}

// ---- prep: keys = mu * softplus(sigma); fp16 copies of keys and mu --------
__global__ __launch_bounds__(256) void prep_w(const float* __restrict__ mu,
                                              const float* __restrict__ sg,
                                              _Float16* __restrict__ kh,
                                              _Float16* __restrict__ mh) {
  const long long i = (long long)(blockIdx.x * blockDim.x + threadIdx.x) * 4;
  f4 m4 = *(const f4*)(mu + i);
  f4 s4 = *(const f4*)(sg + i);
  h4 ok, om;
#pragma unroll
  for (int j = 0; j < 4; ++j) {
    float s  = s4[j];
    float sp = (s > 20.0f) ? s : log1pf(expf(s));
    ok[j] = (_Float16)(m4[j] * sp);
    om[j] = (_Float16)m4[j];
  }
  *(h4*)(kh + i) = ok;
  *(h4*)(mh + i) = om;
}

// ---- fused dual GEMM: scores = Xh*Khs^T, lin = Xh*Mh^T, epilogue ----------
// Xh [M][K], Kh/Mh [N][K] (both operands K-contiguous, "B^T input" GEMM)
__global__ __launch_bounds__(256, 2) void dual_gemm(
    const _Float16* __restrict__ Xh, const _Float16* __restrict__ Kh,
    const _Float16* __restrict__ Mh, const float* __restrict__ gate,
    const float* __restrict__ bias, float* __restrict__ out0,
    float* __restrict__ out1, float* __restrict__ out2) {
  __shared__ _Float16 lds[(BM + 2 * BN) * BK];  // 48 KiB
  _Float16* ldsA = lds;
  _Float16* ldsK = lds + BM * BK;
  _Float16* ldsM = lds + (BM + BN) * BK;

  const int tid  = threadIdx.x;
  const int lane = tid & 63;
  const int wid  = tid >> 6;       // 0..3
  const int wm   = wid >> 1;       // wave row  (2x2 wave grid, 64x64 each)
  const int wn   = wid & 1;        // wave col
  const int lr   = lane & 15;
  const int lk   = lane >> 4;

  const int bn0 = blockIdx.x * BN;
  const int bm0 = blockIdx.y * BM;

  // staging geometry: each tile = 128 rows x 64 f16 = 128B/row = 8x16B chunks
  // chunk c = wid*256 + i*64 + lane  (i=0..3); row = c>>3, kc = c&7
  const int c0   = wid * 256 + lane;
  const int crow = c0 >> 3;
  const int ckc  = c0 & 7;
  const _Float16* aB = Xh + (size_t)(bm0 + crow) * Kdim + ckc * 8;
  const _Float16* kB = Kh + (size_t)(bn0 + crow) * Kdim + ckc * 8;
  const _Float16* mB = Mh + (size_t)(bn0 + crow) * Kdim + ckc * 8;
  char* ldsAb = (char*)ldsA + wid * 4096;  // + i*1024, lane*16 implicit
  char* ldsKb = (char*)ldsK + wid * 4096;
  char* ldsMb = (char*)ldsM + wid * 4096;

  f4 accS[4][4], accL[4][4];
#pragma unroll
  for (int m = 0; m < 4; ++m)
#pragma unroll
    for (int n = 0; n < 4; ++n) {
      accS[m][n] = (f4){0.f, 0.f, 0.f, 0.f};
      accL[m][n] = (f4){0.f, 0.f, 0.f, 0.f};
    }

  for (int kt = 0; kt < Kdim / BK; ++kt) {
    __syncthreads();  // previous compute done before overwrite
#pragma unroll
    for (int i = 0; i < 4; ++i) {
      const size_t go = (size_t)kt * BK + (size_t)i * 8 * Kdim;
      gld_lds16(aB + go, ldsAb + i * 1024);
      gld_lds16(kB + go, ldsKb + i * 1024);
      gld_lds16(mB + go, ldsMb + i * 1024);
    }
    __syncthreads();  // compiler drains vmcnt(0) before barrier

#pragma unroll
    for (int ks = 0; ks < BK / 32; ++ks) {
      h8 af[4], kf[4], mf[4];
#pragma unroll
      for (int m = 0; m < 4; ++m)
        af[m] = *(const h8*)&ldsA[(wm * 64 + m * 16 + lr) * BK + ks * 32 + lk * 8];
#pragma unroll
      for (int n = 0; n < 4; ++n) {
        kf[n] = *(const h8*)&ldsK[(wn * 64 + n * 16 + lr) * BK + ks * 32 + lk * 8];
        mf[n] = *(const h8*)&ldsM[(wn * 64 + n * 16 + lr) * BK + ks * 32 + lk * 8];
      }
#pragma unroll
      for (int m = 0; m < 4; ++m)
#pragma unroll
        for (int n = 0; n < 4; ++n) {
          accS[m][n] = __builtin_amdgcn_mfma_f32_16x16x32_f16(af[m], kf[n], accS[m][n], 0, 0, 0);
          accL[m][n] = __builtin_amdgcn_mfma_f32_16x16x32_f16(af[m], mf[n], accL[m][n], 0, 0, 0);
        }
    }
  }

  // epilogue: scores scale, relu gate, bias; write 3 regions
  const float inv = 0.022097086912079608f;  // 1/sqrt(2048)
#pragma unroll
  for (int n = 0; n < 4; ++n) {
    const int c = bn0 + wn * 64 + n * 16 + lr;
    const float g  = gate[c];
    const float bz = bias[c];
#pragma unroll
    for (int m = 0; m < 4; ++m) {
      const int r0 = bm0 + wm * 64 + m * 16 + lk * 4;
#pragma unroll
      for (int j = 0; j < 4; ++j) {
        const long long idx = (long long)(r0 + j) * Ndim + c;
        const float sc = accS[m][n][j] * inv;
        const float rw = fmaxf(sc - g, 0.0f);
        const float ov = rw * accL[m][n][j] + bz;
        out1[idx] = sc;   // scores
        out0[idx] = ov;   // final_output
        out2[idx] = ov;   // output
      }
    }
  }
}

extern "C" void kernel_launch(void* const* d_in, const int* in_sizes, int n_in,
                              void* d_out, int out_size, void* d_ws, size_t ws_size,
                              hipStream_t stream) {
  const float* x    = (const float*)d_in[0];
  const float* mu   = (const float*)d_in[1];
  const float* sg   = (const float*)d_in[2];
  const float* gate = (const float*)d_in[3];
  const float* bias = (const float*)d_in[4];
  float* out = (float*)d_out;

  _Float16* xh = (_Float16*)d_ws;                 // 16M f16 = 32 MiB
  _Float16* kh = xh + 16777216;                   // keys fp16
  _Float16* mh = kh + 16777216;                   // mu fp16  (total 96 MiB)

  prep_x<<<16384, 256, 0, stream>>>(x, xh);                    // 16M elems /4
  prep_w<<<16384, 256, 0, stream>>>(mu, sg, kh, mh);

  dim3 grid(Ndim / BN, Mdim / BM);  // 64 x 64
  dual_gemm<<<grid, 256, 0, stream>>>(xh, kh, mh, gate, bias,
                                      out, out + OFF_SCORES, out + OFF_OUT);
}

// Round 3
// 1408.114 us; speedup vs baseline: 1.0926x; 1.0926x over previous
//
#include <hip/hip_runtime.h>
#include <cstdint>

typedef _Float16 h8 __attribute__((ext_vector_type(8)));
typedef _Float16 h4 __attribute__((ext_vector_type(4)));
typedef float    f4 __attribute__((ext_vector_type(4)));

static constexpr int Mdim = 8192;   // B*S rows
static constexpr int Ndim = 8192;   // D_OUT
static constexpr int Kdim = 2048;   // D_IN
static constexpr int BM = 256, BNP = 256, BK = 64;  // BNP = B' rows per block
static constexpr long long OFF_SCORES = 67108864LL;
static constexpr long long OFF_OUT    = 134217728LL;

__device__ __forceinline__ void gld_lds16(const void* g, void* l) {
  __builtin_amdgcn_global_load_lds(
      (__attribute__((address_space(1))) void*)(uintptr_t)g,
      (__attribute__((address_space(3))) void*)l, 16, 0, 0);
}

// ---- prep: x fp32 -> fp16 -------------------------------------------------
__global__ __launch_bounds__(256) void prep_x(const float* __restrict__ x,
                                              _Float16* __restrict__ xh) {
  const long long i = (long long)(blockIdx.x * blockDim.x + threadIdx.x) * 4;
  f4 v = *(const f4*)(x + i);
  h4 h;
  h[0] = (_Float16)v[0]; h[1] = (_Float16)v[1];
  h[2] = (_Float16)v[2]; h[3] = (_Float16)v[3];
  *(h4*)(xh + i) = h;
}

// ---- prep: B' interleaved: rows [32b,32b+16) = keys block b, [32b+16,32b+32) = mu
__global__ __launch_bounds__(256) void prep_w(const float* __restrict__ mu,
                                              const float* __restrict__ sg,
                                              _Float16* __restrict__ Bp) {
  const long long i = (long long)(blockIdx.x * blockDim.x + threadIdx.x) * 4;
  const int r = (int)(i >> 11);        // source row 0..8191 (Kdim=2048)
  const int k = (int)(i & 2047);
  const int rb = ((r >> 4) << 5) | (r & 15);  // keys row in B'
  f4 m4 = *(const f4*)(mu + i);
  f4 s4 = *(const f4*)(sg + i);
  h4 ok, om;
#pragma unroll
  for (int j = 0; j < 4; ++j) {
    float s  = s4[j];
    float sp = (s > 20.0f) ? s : log1pf(expf(s));
    ok[j] = (_Float16)(m4[j] * sp);
    om[j] = (_Float16)m4[j];
  }
  *(h4*)(Bp + (size_t)rb * Kdim + k) = ok;        // keys
  *(h4*)(Bp + (size_t)(rb + 16) * Kdim + k) = om; // mu
}

// ---- 256x256 8-phase fused GEMM + epilogue --------------------------------
// X [M][K] f16, Bp [2N][K] f16 (interleaved keys/mu). LDS layout per buffer:
// [mat A/B][256 rows][64 f16] row-major, 16B chunks XOR-swizzled: ch' = ch ^ (row&7).
__global__ __launch_bounds__(512, 2) void dual_gemm(
    const _Float16* __restrict__ X, const _Float16* __restrict__ Bp,
    const float* __restrict__ gate, const float* __restrict__ bias,
    float* __restrict__ out0, float* __restrict__ out1,
    float* __restrict__ out2) {
  __shared__ _Float16 lds[2][2][256][64];  // [buf][mat][row][col] = 128 KiB

  const int tid  = threadIdx.x;
  const int lane = tid & 63;
  const int w    = tid >> 6;   // wave 0..7
  const int wm   = w >> 2;     // 0..1
  const int wn   = w & 3;      // 0..3
  const int lr   = lane & 15;
  const int lk   = lane >> 4;

  // bijective XCD swizzle (2048 blocks, 8 XCDs): each XCD gets 4 consecutive mblks
  const int bid  = blockIdx.x;
  const int id2  = (bid & 7) * 256 + (bid >> 3);
  const int mblk = id2 >> 6, nblk = id2 & 63;
  const int bm0  = mblk * BM;
  const int bn0  = nblk * BNP;  // B'-row offset

  // staging geometry: half-tile = 128 rows x 8 chunks(16B) = 1024 chunks;
  // wave w, call i covers chunks w*128 + i*64 + lane (dest linear lane*16)
  const int cc    = w * 128 + lane;
  const int s_row = cc >> 3;                    // local row in half (call0)
  const int s_ch  = (cc & 7) ^ (s_row & 7);     // pre-swizzled source chunk
  const _Float16* gA = X  + (size_t)(bm0 + s_row) * Kdim + s_ch * 8;
  const _Float16* gB = Bp + (size_t)(bn0 + s_row) * Kdim + s_ch * 8;
  char* ldsBase = (char*)&lds[0][0][0][0];
  const uint32_t dOff = (uint32_t)(w * 2048 + lane * 16);

#define STAGE(buf, mat, h, kt) do {                                          \
    const _Float16* g_ = ((mat) ? gB : gA) + (size_t)(h) * 128 * Kdim +      \
                         (size_t)(kt) * BK;                                  \
    char* l_ = ldsBase + (buf) * 65536 + (mat) * 32768 + (h) * 16384 + dOff; \
    gld_lds16(g_, l_);                                                       \
    gld_lds16(g_ + 8 * Kdim, l_ + 1024);                                     \
  } while (0)

  h8 af[4][2], bf[2][2];
#define LOADA(buf, qm) do {                                                  \
    _Pragma("unroll") for (int m_ = 0; m_ < 4; ++m_) {                       \
      const int row_ = (qm) * 128 + wm * 64 + m_ * 16 + lr;                  \
      _Pragma("unroll") for (int ks_ = 0; ks_ < 2; ++ks_) {                  \
        const int ch_ = (ks_ * 4 + lk) ^ (row_ & 7);                         \
        af[m_][ks_] = *(const h8*)(ldsBase + (buf) * 65536 + row_ * 128 +    \
                                   ch_ * 16);                                \
      } } } while (0)
#define LOADB(buf, qn) do {                                                  \
    _Pragma("unroll") for (int n_ = 0; n_ < 2; ++n_) {                       \
      const int row_ = (qn) * 128 + wn * 32 + n_ * 16 + lr;                  \
      _Pragma("unroll") for (int ks_ = 0; ks_ < 2; ++ks_) {                  \
        const int ch_ = (ks_ * 4 + lk) ^ (row_ & 7);                         \
        bf[n_][ks_] = *(const h8*)(ldsBase + (buf) * 65536 + 32768 +         \
                                   row_ * 128 + ch_ * 16);                   \
      } } } while (0)

  f4 acc[8][4];
#pragma unroll
  for (int m = 0; m < 8; ++m)
#pragma unroll
    for (int n = 0; n < 4; ++n) acc[m][n] = (f4){0.f, 0.f, 0.f, 0.f};

#define MMA(qm, qn) do {                                                     \
    _Pragma("unroll") for (int m_ = 0; m_ < 4; ++m_)                         \
    _Pragma("unroll") for (int n_ = 0; n_ < 2; ++n_)                         \
    _Pragma("unroll") for (int ks_ = 0; ks_ < 2; ++ks_)                      \
      acc[(qm) * 4 + m_][(qn) * 2 + n_] =                                    \
          __builtin_amdgcn_mfma_f32_16x16x32_f16(                            \
              af[m_][ks_], bf[n_][ks_], acc[(qm) * 4 + m_][(qn) * 2 + n_],   \
              0, 0, 0);                                                      \
  } while (0)

#define SCHED0 __builtin_amdgcn_sched_barrier(0)
#define BAR    __builtin_amdgcn_s_barrier()
#define WLGKM  do { asm volatile("s_waitcnt lgkmcnt(0)" ::: "memory"); SCHED0; } while (0)
#define VM4    asm volatile("s_waitcnt vmcnt(4)" ::: "memory")
#define PRIO1  __builtin_amdgcn_s_setprio(1)
#define PRIO0  __builtin_amdgcn_s_setprio(0)

  // prologue: tile0 full -> buf0; tile1 A-h0 + B-h1 -> buf1
  STAGE(0, 0, 0, 0); STAGE(0, 0, 1, 0); STAGE(0, 1, 0, 0); STAGE(0, 1, 1, 0);
  STAGE(1, 0, 0, 1); STAGE(1, 1, 1, 1);
  VM4;  // tile0 landed; tile1's 4 loads in flight
  BAR;

  for (int i = 0; i < 16; ++i) {
    const int t1 = 2 * i + 1;
    const int t2 = (2 * i + 2) & 31;
    const int t3 = (2 * i + 3) & 31;
    // ph1: buf0 Q(0,0); stage T1.B-h0 -> buf1
    LOADA(0, 0); LOADB(0, 0);
    STAGE(1, 1, 0, t1);
    SCHED0; BAR; WLGKM;
    PRIO1; MMA(0, 0); PRIO0;
    BAR;
    // ph2: buf0 Q(0,1); stage T1.A-h1 -> buf1
    LOADB(0, 1);
    STAGE(1, 0, 1, t1);
    SCHED0; BAR; WLGKM;
    PRIO1; MMA(0, 1); PRIO0;
    BAR;
    // ph3: buf0 Q(1,1); stage T2.A-h0 -> buf0
    LOADA(0, 1);
    STAGE(0, 0, 0, t2);
    SCHED0; BAR; WLGKM;
    PRIO1; MMA(1, 1); PRIO0;
    BAR;
    // ph4: buf0 Q(1,0); stage T2.B-h1 -> buf0; counted vmcnt
    LOADB(0, 0);
    STAGE(0, 1, 1, t2);
    VM4;
    SCHED0; BAR; WLGKM;
    PRIO1; MMA(1, 0); PRIO0;
    BAR;
    // ph5: buf1 Q(0,0); stage T2.B-h0 -> buf0
    LOADA(1, 0); LOADB(1, 0);
    STAGE(0, 1, 0, t2);
    SCHED0; BAR; WLGKM;
    PRIO1; MMA(0, 0); PRIO0;
    BAR;
    // ph6: buf1 Q(0,1); stage T2.A-h1 -> buf0
    LOADB(1, 1);
    STAGE(0, 0, 1, t2);
    SCHED0; BAR; WLGKM;
    PRIO1; MMA(0, 1); PRIO0;
    BAR;
    // ph7: buf1 Q(1,1); stage T3.A-h0 -> buf1
    LOADA(1, 1);
    STAGE(1, 0, 0, t3);
    SCHED0; BAR; WLGKM;
    PRIO1; MMA(1, 1); PRIO0;
    BAR;
    // ph8: buf1 Q(1,0); stage T3.B-h1 -> buf1; counted vmcnt
    LOADB(1, 0);
    STAGE(1, 1, 1, t3);
    VM4;
    SCHED0; BAR; WLGKM;
    PRIO1; MMA(1, 0); PRIO0;
    BAR;
  }

  // epilogue: fragment pairs (qn*2+0 = scores, qn*2+1 = lin) share output cols
  const float inv = 0.022097086912079608f;  // 1/sqrt(2048)
#pragma unroll
  for (int qn = 0; qn < 2; ++qn) {
    const int col = (bn0 >> 1) + qn * 64 + wn * 16 + lr;
    const float g  = gate[col];
    const float bz = bias[col];
#pragma unroll
    for (int mi = 0; mi < 8; ++mi) {
      const int qm = mi >> 2;
      const int r0 = bm0 + qm * 128 + wm * 64 + (mi & 3) * 16 + lk * 4;
      f4 s4 = acc[mi][qn * 2 + 0];
      f4 l4 = acc[mi][qn * 2 + 1];
#pragma unroll
      for (int j = 0; j < 4; ++j) {
        const long long idx = (long long)(r0 + j) * Ndim + col;
        const float sc = s4[j] * inv;
        const float ov = fmaxf(sc - g, 0.0f) * l4[j] + bz;
        out1[idx] = sc;   // scores
        out0[idx] = ov;   // final_output
        out2[idx] = ov;   // output
      }
    }
  }
#undef STAGE
#undef LOADA
#undef LOADB
#undef MMA
#undef SCHED0
#undef BAR
#undef WLGKM
#undef VM4
#undef PRIO1
#undef PRIO0
}

extern "C" void kernel_launch(void* const* d_in, const int* in_sizes, int n_in,
                              void* d_out, int out_size, void* d_ws, size_t ws_size,
                              hipStream_t stream) {
  const float* x    = (const float*)d_in[0];
  const float* mu   = (const float*)d_in[1];
  const float* sg   = (const float*)d_in[2];
  const float* gate = (const float*)d_in[3];
  const float* bias = (const float*)d_in[4];
  float* out = (float*)d_out;

  _Float16* xh = (_Float16*)d_ws;     // 32 MiB
  _Float16* bp = xh + 16777216;       // 64 MiB interleaved B'

  prep_x<<<16384, 256, 0, stream>>>(x, xh);
  prep_w<<<16384, 256, 0, stream>>>(mu, sg, bp);

  dual_gemm<<<2048, 512, 0, stream>>>(xh, bp, gate, bias,
                                      out, out + OFF_SCORES, out + OFF_OUT);
}